// Round 9
// baseline (1151.593 us; speedup 1.0000x reference)
//
#include <hip/hip_runtime.h>
#include <hip/hip_bf16.h>

// Problem dims
constexpr int NV   = 10000;  // vocab
constexpr int NE   = 512;    // embed
constexpr int NENC = 2048;   // encoder dim
constexpr int ND   = 512;    // decoder dim
constexpr int NA   = 512;    // attention dim
constexpr int NB   = 64;     // batch
constexpr int NL   = 49;     // locations
constexpr int NT   = 20;     // steps
constexpr int KX   = NE + NENC + ND;  // 3072 : x = [emb | context | h]
constexpr int KIH  = NE + NENC;       // 2560 : W_ih inner dim

typedef short bfrag __attribute__((ext_vector_type(8)));   // 8 bf16 (4 VGPRs)
typedef float f32x4 __attribute__((ext_vector_type(4)));   // MFMA acc

__device__ __forceinline__ float us2f(unsigned short u) {
    union { unsigned int i; float f; } x; x.i = (unsigned int)u << 16; return x.f;
}
__device__ __forceinline__ unsigned short f2us(float f) {  // RNE f32->bf16
    union { float f_; unsigned int u; } x; x.f_ = f;
    unsigned int r = (x.u + 0x7fffu + ((x.u >> 16) & 1u)) >> 16;
    return (unsigned short)r;
}

// ---------------------------------------------------------------------------
// K_prep: all one-time data prep in ONE launch (block-range dispatch):
//   [0,6272)        enc  f32 -> encb bf16   (1024 elems/block)
//   [6272,11392)    Wih  f32 -> Wihb bf16
//   [11392,12416)   Whh  f32 -> Whhb bf16
//   [12416,12672)   Wda  f32 -> Wdab bf16 (NON-transposed, for in-att dp)
//   [12672,20752)   4 transposes (Wh0,Wc0,Wea,Wout -> bf16 T)
//   [20752,21264)   mean over L -> meanbf bf16 (8 blocks/b)
// All ranges independent.
// ---------------------------------------------------------------------------
__launch_bounds__(256)
__global__ void k_prep(const float* __restrict__ enc, unsigned short* __restrict__ encb,
                       const float* __restrict__ Wih, unsigned short* __restrict__ Wihb,
                       const float* __restrict__ Whh, unsigned short* __restrict__ Whhb,
                       const float* __restrict__ Wda, unsigned short* __restrict__ Wdab,
                       const float* __restrict__ Wh0, const float* __restrict__ Wc0,
                       const float* __restrict__ Wea, const float* __restrict__ Wout,
                       unsigned short* __restrict__ WicT, unsigned short* __restrict__ WeaT,
                       unsigned short* __restrict__ WoutT,
                       unsigned short* __restrict__ meanbf)
{
    int bid = blockIdx.x;
    if (bid < 12672) {                         // ---- cvt f32->bf16 ----
        const float* src; unsigned short* dst;
        if (bid < 6272)       { src = enc; dst = encb; }
        else if (bid < 11392) { src = Wih; dst = Wihb; bid -= 6272; }
        else if (bid < 12416) { src = Whh; dst = Whhb; bid -= 11392; }
        else                  { src = Wda; dst = Wdab; bid -= 12416; }
        const int i = bid * 1024 + threadIdx.x * 4;
        float4 v = *(const float4*)(src + i);
        dst[i + 0] = f2us(v.x); dst[i + 1] = f2us(v.y);
        dst[i + 2] = f2us(v.z); dst[i + 3] = f2us(v.w);
    } else if (bid < 20752) {                  // ---- transposes ----
        bid -= 12672;
        __shared__ float t[32][33];
        const float* src; unsigned short* dst; int K, N, nCols;
        if (bid < 1024)      { src = Wh0;  dst = WicT;                     K = NENC; N = ND; nCols = 16; }
        else if (bid < 2048) { src = Wc0;  dst = WicT + (size_t)ND * NENC; K = NENC; N = ND; nCols = 16; bid -= 1024; }
        else if (bid < 3072) { src = Wea;  dst = WeaT;                     K = NENC; N = NA; nCols = 16; bid -= 2048; }
        else                 { src = Wout; dst = WoutT;                    K = ND;   N = NV; nCols = 313; bid -= 3072; }
        const int nb = (bid % nCols) * 32, kb = (bid / nCols) * 32;
        const int tx = threadIdx.x & 31, ty = threadIdx.x >> 5;
        #pragma unroll
        for (int i = ty; i < 32; i += 8) {
            int n = nb + tx;
            t[i][tx] = (n < N) ? src[(size_t)(kb + i) * N + n] : 0.f;
        }
        __syncthreads();
        #pragma unroll
        for (int i = ty; i < 32; i += 8) {
            int n = nb + i;
            if (n < N) dst[(size_t)n * K + kb + tx] = f2us(t[tx][i]);
        }
    } else {                                   // ---- mean over L ----
        bid -= 20752;
        const int b = bid >> 3;
        const int e = (bid & 7) * 256 + threadIdx.x;
        const float* p = enc + (size_t)b * NL * NENC + e;
        float s = 0.f;
        #pragma unroll 7
        for (int l = 0; l < NL; ++l) s += p[(size_t)l * NENC];
        meanbf[(size_t)b * NENC + e] = f2us(s * (1.0f / NL));
    }
}

// ---------------------------------------------------------------------------
// K_mfma2: encproj + init GEMMs in ONE launch, both 8-wave K-split-2.
//  blocks [0,392): epb(3136,512) = encb @ WeaT^T + bea (r6 tiling + K-split).
//  blocks [392,456): [h|c](64,1024) = meanbf @ WicT^T + bias.
// ---------------------------------------------------------------------------
__launch_bounds__(512)
__global__ void k_mfma2(const unsigned short* __restrict__ encb,
                        const unsigned short* __restrict__ WeaT,
                        const float* __restrict__ bea,
                        unsigned short* __restrict__ epb,
                        const unsigned short* __restrict__ meanbf,
                        const unsigned short* __restrict__ WicT,
                        const float* __restrict__ bh, const float* __restrict__ bc,
                        unsigned short* __restrict__ hbf, float* __restrict__ c)
{
    __shared__ float comb[4 * 64 * 16];   // 16 KB
    const int tid = threadIdx.x;
    const int wave = tid >> 6, lane = tid & 63;
    const int r = lane & 15, quad = lane >> 4;
    if (blockIdx.x < 392) {
        const int j = ((int)blockIdx.x & 7) * 49 + ((int)blockIdx.x >> 3);  // bijective
        const int ng = j & 7, mg = j >> 3;
        const int ow = wave & 3, kh = wave >> 2;      // output quadrant, k-half
        const int wm = ow >> 1, wn = ow & 1;
        const int m0 = mg * 64 + wm * 32;
        const int n0 = ng * 64 + wn * 32;
        const int kb = kh * (NENC / 2);
        const unsigned short* ap0 = encb + (size_t)(m0 + r) * NENC + kb + quad * 8;
        const unsigned short* ap1 = ap0 + (size_t)16 * NENC;
        const unsigned short* bp0 = WeaT + (size_t)(n0 + r) * NENC + kb + quad * 8;
        const unsigned short* bp1 = bp0 + (size_t)16 * NENC;
        f32x4 a00 = {0.f,0.f,0.f,0.f}, a01 = {0.f,0.f,0.f,0.f};
        f32x4 a10 = {0.f,0.f,0.f,0.f}, a11 = {0.f,0.f,0.f,0.f};
        #pragma unroll 4
        for (int k = 0; k < NENC / 2; k += 32) {
            bfrag x0 = *(const bfrag*)(ap0 + k);
            bfrag x1 = *(const bfrag*)(ap1 + k);
            bfrag y0 = *(const bfrag*)(bp0 + k);
            bfrag y1 = *(const bfrag*)(bp1 + k);
            a00 = __builtin_amdgcn_mfma_f32_16x16x32_bf16(x0, y0, a00, 0, 0, 0);
            a01 = __builtin_amdgcn_mfma_f32_16x16x32_bf16(x0, y1, a01, 0, 0, 0);
            a10 = __builtin_amdgcn_mfma_f32_16x16x32_bf16(x1, y0, a10, 0, 0, 0);
            a11 = __builtin_amdgcn_mfma_f32_16x16x32_bf16(x1, y1, a11, 0, 0, 0);
        }
        if (kh == 1) {
            float* d = comb + (ow * 64 + lane) * 16;
            #pragma unroll
            for (int i = 0; i < 4; ++i) {
                d[i]      = a00[i];
                d[4 + i]  = a01[i];
                d[8 + i]  = a10[i];
                d[12 + i] = a11[i];
            }
        }
        __syncthreads();
        if (kh == 0) {
            const float* d = comb + (ow * 64 + lane) * 16;
            const float bv0 = bea[n0 + r], bv1 = bea[n0 + 16 + r];
            #pragma unroll
            for (int i = 0; i < 4; ++i) {
                int ma = m0 + quad * 4 + i, mb = ma + 16;
                epb[(size_t)ma * NA + n0 + r]      = f2us(a00[i] + d[i]      + bv0);
                epb[(size_t)ma * NA + n0 + 16 + r] = f2us(a01[i] + d[4 + i]  + bv1);
                epb[(size_t)mb * NA + n0 + r]      = f2us(a10[i] + d[8 + i]  + bv0);
                epb[(size_t)mb * NA + n0 + 16 + r] = f2us(a11[i] + d[12 + i] + bv1);
            }
        }
    } else {
        // init: [h|c](64,1024) — block = one 16-col n-tile, 4 m-tiles x 2 k-halves
        const int nt = (int)blockIdx.x - 392;         // 0..63
        const int n0 = nt * 16;
        const int mtile = wave & 3, kh = wave >> 2;
        const int m0 = mtile * 16;
        const int kb = kh * (NENC / 2);
        const unsigned short* ap = meanbf + (size_t)(m0 + r) * NENC + kb + quad * 8;
        const unsigned short* bp = WicT   + (size_t)(n0 + r) * NENC + kb + quad * 8;
        f32x4 acc = {0.f, 0.f, 0.f, 0.f};
        #pragma unroll 4
        for (int k = 0; k < NENC / 2; k += 32) {
            bfrag a = *(const bfrag*)(ap + k);
            bfrag b = *(const bfrag*)(bp + k);
            acc = __builtin_amdgcn_mfma_f32_16x16x32_bf16(a, b, acc, 0, 0, 0);
        }
        if (kh == 1) {
            float* d = comb + (mtile * 64 + lane) * 4;
            #pragma unroll
            for (int i = 0; i < 4; ++i) d[i] = acc[i];
        }
        __syncthreads();
        if (kh == 0) {
            const float* d = comb + (mtile * 64 + lane) * 4;
            const int n = n0 + r;
            const bool isC = n >= ND;
            const float bv = isC ? bc[n - ND] : bh[n];
            #pragma unroll
            for (int i = 0; i < 4; ++i) {
                int m = m0 + quad * 4 + i;
                float v = acc[i] + d[i] + bv;
                if (isC) c[(size_t)m * ND + (n - ND)] = v;
                else     hbf[(size_t)m * ND + n] = f2us(v);
            }
        }
    }
}

// ---------------------------------------------------------------------------
// logits tile-tasks in [lo,hi) over workers; 8 waves = 2 task slots.
// ---------------------------------------------------------------------------
__device__ __forceinline__ void logits_tasks(int t, int lo, int hi,
    int worker, int nworkers, int wave, int lane,
    const unsigned short* hbf, const unsigned short* WoutT,
    const float* bout, float* out)
{
    const int slot = wave >> 2, w4 = wave & 3;
    const int r = lane & 15, quad = lane >> 4;
    const int m0 = w4 * 16;
    for (int task = lo + worker * 2 + slot; task < hi; task += nworkers * 2) {
        const int n0 = task * 16;                      // task < 625
        const unsigned short* ap = hbf + (size_t)(m0 + r) * ND + quad * 8;
        const unsigned short* bp = WoutT + (size_t)(n0 + r) * ND + quad * 8;
        f32x4 acc = {0.f, 0.f, 0.f, 0.f};
        #pragma unroll
        for (int k = 0; k < ND; k += 32) {
            bfrag a = *(const bfrag*)(ap + k);
            bfrag b = *(const bfrag*)(bp + k);
            acc = __builtin_amdgcn_mfma_f32_16x16x32_bf16(a, b, acc, 0, 0, 0);
        }
        const float bv = bout[n0 + r];
        #pragma unroll
        for (int i = 0; i < 4; ++i) {
            int m = m0 + quad * 4 + i;
            out[((size_t)m * NT + t) * NV + n0 + r] = acc[i] + bv;
        }
    }
}

// ---------------------------------------------------------------------------
// att body: one 512-thread block per b. dp computed IN-BLOCK via vector FMA
// against non-transposed Wdab: thread a does dp[a] = sum_k h[k]*Wda[k][a].
// Per k-iter the 512 threads read one contiguous 1KB row (coalesced,
// L2-shared across the ~8 att blocks per XCD). h broadcast from LDS.
// NO redundant MFMA (the r5/r7 mistake). ushort4 context loads (fast path).
// ---------------------------------------------------------------------------
__device__ __forceinline__ void att_body(int t, int b, int tid,
    const unsigned short* hcur, const unsigned short* epb,
    const unsigned short* encb, const unsigned short* Wdab,
    const float* bda, const float* wf, const float* bfs,
    const float* embt, const int* caps, unsigned short* x, float* alpha_out,
    float* dp /*smem 512*/, float* al /*smem 64*/, float* hs /*smem 512*/)
{
    const unsigned short hv = hcur[(size_t)b * ND + tid];
    x[(size_t)b * KX + NE + NENC + tid] = hv;                          // h tail
    hs[tid] = us2f(hv);
    const int tok = caps[b * NT + t];
    x[(size_t)b * KX + tid] = f2us(embt[(size_t)tok * NE + tid]);      // emb head
    __syncthreads();

    // dp[a] = sum_k hs[k] * Wdab[k][a]  (f32 FMA, coalesced rows)
    {
        float acc = 0.f;
        const unsigned short* wp = Wdab + tid;
        #pragma unroll 8
        for (int k = 0; k < ND; ++k)
            acc = fmaf(hs[k], us2f(wp[(size_t)k * NA]), acc);
        dp[tid] = acc + bda[tid];
    }
    __syncthreads();

    const int wave = tid >> 6, lane = tid & 63;
    const float bfull = bfs[0];
    for (int l = wave; l < NL; l += 8) {
        const unsigned short* ep = epb + ((size_t)b * NL + l) * NA;
        float s = 0.f;
        #pragma unroll
        for (int a = lane; a < NA; a += 64) {
            float v = us2f(ep[a]) + dp[a];
            v = v > 0.f ? v : 0.f;
            s = fmaf(v, wf[a], s);
        }
        #pragma unroll
        for (int off = 32; off > 0; off >>= 1) s += __shfl_down(s, off, 64);
        if (lane == 0) al[l] = s + bfull;
    }
    __syncthreads();

    if (tid < 64) {
        float v = (tid < NL) ? al[tid] : -1e30f;
        float m = v;
        #pragma unroll
        for (int off = 32; off > 0; off >>= 1) m = fmaxf(m, __shfl_xor(m, off, 64));
        float e = (tid < NL) ? expf(v - m) : 0.f;
        float s = e;
        #pragma unroll
        for (int off = 32; off > 0; off >>= 1) s += __shfl_xor(s, off, 64);
        float a = e / s;
        if (tid < NL) {
            al[tid] = a;
            alpha_out[((size_t)b * NT + t) * NL + tid] = a;
        }
    }
    __syncthreads();

    {   // context: thread covers 4 consecutive e (512*4 = 2048), ushort4
        const int e = tid * 4;
        const unsigned short* p = encb + (size_t)b * NL * NENC + e;
        float s0 = 0.f, s1 = 0.f, s2 = 0.f, s3 = 0.f;
        #pragma unroll 7
        for (int l = 0; l < NL; ++l) {
            ushort4 v = *(const ushort4*)(p + (size_t)l * NENC);
            float a = al[l];
            s0 = fmaf(a, us2f(v.x), s0);
            s1 = fmaf(a, us2f(v.y), s1);
            s2 = fmaf(a, us2f(v.z), s2);
            s3 = fmaf(a, us2f(v.w), s3);
        }
        unsigned short* xo = x + (size_t)b * KX + NE + e;
        xo[0] = f2us(s0); xo[1] = f2us(s1); xo[2] = f2us(s2); xo[3] = f2us(s3);
    }
}

// ---------------------------------------------------------------------------
// K_att_logits: blocks 0..63 = att(t) (incl. in-block dp); blocks 64..255 =
// logits(t-1) tasks [0,384) over 192 workers. Grid 256 = 1 block/CU.
// All blocks read-only on hcur.
// ---------------------------------------------------------------------------
__launch_bounds__(512)
__global__ void k_att_logits(int t,
                             const unsigned short* __restrict__ hcur,
                             const unsigned short* __restrict__ epb,
                             const unsigned short* __restrict__ encb,
                             const unsigned short* __restrict__ Wdab,
                             const float* __restrict__ bda,
                             const float* __restrict__ wf,
                             const float* __restrict__ bfs,
                             const float* __restrict__ embt,
                             const int* __restrict__ captions,
                             unsigned short* __restrict__ x,
                             float* __restrict__ alpha_out,
                             const unsigned short* __restrict__ WoutT,
                             const float* __restrict__ bout,
                             float* __restrict__ out)
{
    __shared__ float smem[1088];   // dp 512 | al 64 | hs 512
    const int bid = blockIdx.x, tid = threadIdx.x;
    if (bid < 64) {
        att_body(t, bid, tid, hcur, epb, encb, Wdab, bda, wf, bfs,
                 embt, captions, x, alpha_out, smem, smem + 512, smem + 576);
    } else if (t > 0) {
        logits_tasks(t - 1, 0, 384, bid - 64, 192, tid >> 6, tid & 63,
                     hcur, WoutT, bout, out);
    }
}

// ---------------------------------------------------------------------------
// K_gates_lstm: blocks 0..127 = fused gates GEMM + LSTM (8-wave K-split,
// XCD-grouped bid->(ng,mt)); parallel 256-thread epilogue. Blocks 128..248 =
// logits(t-1) tasks [384,625). h ping-pong for race-freedom.
// ---------------------------------------------------------------------------
__launch_bounds__(512)
__global__ void k_gates_lstm(int t,
                             const unsigned short* __restrict__ x,     // (64,3072)
                             const unsigned short* __restrict__ Wihb,  // (2048,2560)
                             const unsigned short* __restrict__ Whhb,  // (2048,512)
                             const float* __restrict__ bih, const float* __restrict__ bhh,
                             unsigned short* __restrict__ hnxt, float* __restrict__ c,
                             const unsigned short* __restrict__ hcur,
                             const unsigned short* __restrict__ WoutT,
                             const float* __restrict__ bout,
                             float* __restrict__ out)
{
    __shared__ float part[8 * 4 * 16 * 16];   // 32 KB
    const int bid = blockIdx.x;
    const int wave = threadIdx.x >> 6, lane = threadIdx.x & 63;
    if (bid >= 128) {
        if (t > 0)
            logits_tasks(t - 1, 384, 625, bid - 128, 121, wave, lane,
                         hcur, WoutT, bout, out);
        return;
    }
    // XCD-grouped mapping: bid%8 = ng>>2 for all 4 mt copies of an ng
    const int ng = (bid & 7) * 4 + ((bid >> 3) & 3);
    const int mt = bid >> 5;
    const int m0 = mt * 16, n0 = ng * 16;
    const int r = lane & 15, quad = lane >> 4;
    const int k0 = wave * (KX / 8), k1 = k0 + (KX / 8);   // 384-wide chunks

    const unsigned short* ap = x + (size_t)(m0 + r) * KX + quad * 8;
    const unsigned short* bpih[4];
    const unsigned short* bphh[4];
    #pragma unroll
    for (int g = 0; g < 4; ++g) {
        bpih[g] = Wihb + (size_t)(g * ND + n0 + r) * KIH + quad * 8;
        bphh[g] = Whhb + (size_t)(g * ND + n0 + r) * ND + quad * 8;
    }
    f32x4 acc[4] = {{0.f,0.f,0.f,0.f},{0.f,0.f,0.f,0.f},
                    {0.f,0.f,0.f,0.f},{0.f,0.f,0.f,0.f}};

    const int kiA = (k1 < KIH) ? k1 : KIH;
    #pragma unroll 4
    for (int k = k0; k < kiA; k += 32) {
        bfrag a = *(const bfrag*)(ap + k);
        #pragma unroll
        for (int g = 0; g < 4; ++g) {
            bfrag b = *(const bfrag*)(bpih[g] + k);
            acc[g] = __builtin_amdgcn_mfma_f32_16x16x32_bf16(a, b, acc[g], 0, 0, 0);
        }
    }
    const int kiB = (k0 > KIH) ? k0 : KIH;
    #pragma unroll 4
    for (int k = kiB; k < k1; k += 32) {
        bfrag a = *(const bfrag*)(ap + k);
        #pragma unroll
        for (int g = 0; g < 4; ++g) {
            bfrag b = *(const bfrag*)(bphh[g] + (k - KIH));
            acc[g] = __builtin_amdgcn_mfma_f32_16x16x32_bf16(a, b, acc[g], 0, 0, 0);
        }
    }

    #pragma unroll
    for (int g = 0; g < 4; ++g)
        #pragma unroll
        for (int i = 0; i < 4; ++i)
            part[((wave * 4 + g) * 16 + quad * 4 + i) * 16 + r] = acc[g][i];
    __syncthreads();

    if (threadIdx.x < 256) {
        const int row = threadIdx.x >> 4, col = threadIdx.x & 15;
        float gs[4];
        #pragma unroll
        for (int g = 0; g < 4; ++g) {
            float v = 0.f;
            #pragma unroll
            for (int w = 0; w < 8; ++w)
                v += part[((w * 4 + g) * 16 + row) * 16 + col];
            gs[g] = v;
        }
        const int d = n0 + col;
        const int m = m0 + row;
        float gi = gs[0] + bih[d]        + bhh[d];
        float gf = gs[1] + bih[d + 512]  + bhh[d + 512];
        float gg = gs[2] + bih[d + 1024] + bhh[d + 1024];
        float go = gs[3] + bih[d + 1536] + bhh[d + 1536];
        float ig = 1.f / (1.f + expf(-gi));
        float fg = 1.f / (1.f + expf(-gf));
        float g  = tanhf(gg);
        float og = 1.f / (1.f + expf(-go));
        float cn = fg * c[(size_t)m * ND + d] + ig * g;
        float hn = og * tanhf(cn);
        c[(size_t)m * ND + d] = cn;
        hnxt[(size_t)m * ND + d] = f2us(hn);
    }
}

// ---------------------------------------------------------------------------
// K_logits_fin: full logits for the last step. grid 313 x 512.
// ---------------------------------------------------------------------------
__launch_bounds__(512)
__global__ void k_logits_fin(int t,
                             const unsigned short* __restrict__ hbf,
                             const unsigned short* __restrict__ WoutT,
                             const float* __restrict__ bout,
                             float* __restrict__ out)
{
    logits_tasks(t, 0, 625, blockIdx.x, 313, threadIdx.x >> 6, threadIdx.x & 63,
                 hbf, WoutT, bout, out);
}

// ---------------------------------------------------------------------------
extern "C" void kernel_launch(void* const* d_in, const int* in_sizes, int n_in,
                              void* d_out, int out_size, void* d_ws, size_t ws_size,
                              hipStream_t stream) {
    const float* enc  = (const float*)d_in[0];
    const int*   caps = (const int*)d_in[1];
    const float* embt = (const float*)d_in[2];
    const float* Wea  = (const float*)d_in[3];
    const float* bea  = (const float*)d_in[4];
    const float* Wda  = (const float*)d_in[5];
    const float* bda  = (const float*)d_in[6];
    const float* wf   = (const float*)d_in[7];
    const float* bfs  = (const float*)d_in[8];
    const float* Wih  = (const float*)d_in[9];
    const float* bih  = (const float*)d_in[10];
    const float* Whh  = (const float*)d_in[11];
    const float* bhh  = (const float*)d_in[12];
    const float* Wh0  = (const float*)d_in[13];
    const float* bh0  = (const float*)d_in[14];
    const float* Wc0  = (const float*)d_in[15];
    const float* bc0  = (const float*)d_in[16];
    const float* Wout = (const float*)d_in[17];
    const float* bout = (const float*)d_in[18];

    float* out = (float*)d_out;                       // logits (B,T,V) f32
    float* alpha_out = out + (size_t)NB * NT * NV;    // alphas (B,T,L) f32

    // ---- workspace carve-up (16B aligned throughout) ----
    char* w = (char*)d_ws;
    float* c     = (float*)w;                 w += (size_t)NB * ND * 4;          // 128 KB
    unsigned short* meanbf = (unsigned short*)w; w += (size_t)NB * NENC * 2;     // 256 KB
    unsigned short* hb    = (unsigned short*)w; w += (size_t)2 * NB * ND * 2;    // 128 KB (ping-pong)
    unsigned short* x     = (unsigned short*)w; w += (size_t)NB * KX * 2;        // 384 KB
    unsigned short* epb   = (unsigned short*)w; w += (size_t)NB * NL * NA * 2;   // 3.2 MB
    unsigned short* encb  = (unsigned short*)w; w += (size_t)NB * NL * NENC * 2; // 12.8 MB
    unsigned short* Wihb  = (unsigned short*)w; w += (size_t)4 * ND * KIH * 2;   // 10.5 MB
    unsigned short* Whhb  = (unsigned short*)w; w += (size_t)4 * ND * ND * 2;    // 2 MB
    unsigned short* WeaT  = (unsigned short*)w; w += (size_t)NA * NENC * 2;      // 2 MB
    unsigned short* Wdab  = (unsigned short*)w; w += (size_t)ND * NA * 2;        // 0.5 MB
    unsigned short* WoutT = (unsigned short*)w; w += (size_t)NV * ND * 2;        // 10.2 MB
    unsigned short* WicT  = (unsigned short*)w; w += (size_t)2 * ND * NENC * 2;  // 4 MB

    // ---- one-time setup (2 dispatches) ----
    hipLaunchKernelGGL(k_prep, dim3(21264), dim3(256), 0, stream,
                       enc, encb, Wih, Wihb, Whh, Whhb, Wda, Wdab,
                       Wh0, Wc0, Wea, Wout, WicT, WeaT, WoutT, meanbf);
    hipLaunchKernelGGL(k_mfma2, dim3(456), dim3(512), 0, stream,
                       encb, WeaT, bea, epb, meanbf, WicT, bh0, bc0, hb, c);

    // ---- 20 sequential decoder steps, 2 dispatches each ----
    for (int t = 0; t < NT; ++t) {
        unsigned short* hcur = hb + (size_t)(t & 1) * NB * ND;
        unsigned short* hnxt = hb + (size_t)((t + 1) & 1) * NB * ND;
        hipLaunchKernelGGL(k_att_logits, dim3(256), dim3(512), 0, stream,
                           t, hcur, epb, encb, Wdab, bda, wf, bfs, embt, caps,
                           x, alpha_out, WoutT, bout, out);
        hipLaunchKernelGGL(k_gates_lstm, dim3(249), dim3(512), 0, stream,
                           t, x, Wihb, Whhb, bih, bhh, hnxt, c,
                           hcur, WoutT, bout, out);
    }
    // logits for the last step (h_20 lives in hb[(NT)&1] = hb[0])
    hipLaunchKernelGGL(k_logits_fin, dim3(313), dim3(512), 0, stream,
                       NT - 1, hb + (size_t)(NT & 1) * NB * ND, WoutT, bout, out);
}

// Round 10
// 1147.522 us; speedup vs baseline: 1.0035x; 1.0035x over previous
//
#include <hip/hip_runtime.h>
#include <hip/hip_bf16.h>

// Problem dims
constexpr int NV   = 10000;  // vocab
constexpr int NE   = 512;    // embed
constexpr int NENC = 2048;   // encoder dim
constexpr int ND   = 512;    // decoder dim
constexpr int NA   = 512;    // attention dim
constexpr int NB   = 64;     // batch
constexpr int NL   = 49;     // locations
constexpr int NT   = 20;     // steps
constexpr int KX   = NE + NENC + ND;  // 3072 : x = [emb | context | h]
constexpr int KIH  = NE + NENC;       // 2560 : W_ih inner dim

typedef short bfrag __attribute__((ext_vector_type(8)));   // 8 bf16 (4 VGPRs)
typedef float f32x4 __attribute__((ext_vector_type(4)));   // MFMA acc

__device__ __forceinline__ float us2f(unsigned short u) {
    union { unsigned int i; float f; } x; x.i = (unsigned int)u << 16; return x.f;
}
__device__ __forceinline__ unsigned short f2us(float f) {  // RNE f32->bf16
    union { float f_; unsigned int u; } x; x.f_ = f;
    unsigned int r = (x.u + 0x7fffu + ((x.u >> 16) & 1u)) >> 16;
    return (unsigned short)r;
}

// ---------------------------------------------------------------------------
// K_prep: all one-time data prep in ONE launch (block-range dispatch):
//   [0,6272)        enc  f32 -> encb bf16   (1024 elems/block)
//   [6272,11392)    Wih  f32 -> Wihb bf16
//   [11392,12416)   Whh  f32 -> Whhb bf16
//   [12416,20752)   5 transposes (Wh0,Wc0,Wea,Wda,Wout -> bf16 T)
//   [20752,21264)   mean over L -> meanbf bf16 (8 blocks/b)
//   [21264]         zero the per-step producer flags (replay-safe)
// ---------------------------------------------------------------------------
__launch_bounds__(256)
__global__ void k_prep(const float* __restrict__ enc, unsigned short* __restrict__ encb,
                       const float* __restrict__ Wih, unsigned short* __restrict__ Wihb,
                       const float* __restrict__ Whh, unsigned short* __restrict__ Whhb,
                       const float* __restrict__ Wh0, const float* __restrict__ Wc0,
                       const float* __restrict__ Wea, const float* __restrict__ Wda,
                       const float* __restrict__ Wout,
                       unsigned short* __restrict__ WicT, unsigned short* __restrict__ WeaT,
                       unsigned short* __restrict__ WdaT, unsigned short* __restrict__ WoutT,
                       unsigned short* __restrict__ meanbf, int* __restrict__ flags)
{
    int bid = blockIdx.x;
    if (bid < 12416) {                         // ---- cvt f32->bf16 ----
        const float* src; unsigned short* dst;
        if (bid < 6272)       { src = enc; dst = encb; }
        else if (bid < 11392) { src = Wih; dst = Wihb; bid -= 6272; }
        else                  { src = Whh; dst = Whhb; bid -= 11392; }
        const int i = bid * 1024 + threadIdx.x * 4;
        float4 v = *(const float4*)(src + i);
        dst[i + 0] = f2us(v.x); dst[i + 1] = f2us(v.y);
        dst[i + 2] = f2us(v.z); dst[i + 3] = f2us(v.w);
    } else if (bid < 20752) {                  // ---- transposes ----
        bid -= 12416;
        __shared__ float t[32][33];
        const float* src; unsigned short* dst; int K, N, nCols;
        if (bid < 1024)      { src = Wh0;  dst = WicT;                     K = NENC; N = ND; nCols = 16; }
        else if (bid < 2048) { src = Wc0;  dst = WicT + (size_t)ND * NENC; K = NENC; N = ND; nCols = 16; bid -= 1024; }
        else if (bid < 3072) { src = Wea;  dst = WeaT;                     K = NENC; N = NA; nCols = 16; bid -= 2048; }
        else if (bid < 3328) { src = Wda;  dst = WdaT;                     K = ND;   N = NA; nCols = 16; bid -= 3072; }
        else                 { src = Wout; dst = WoutT;                    K = ND;   N = NV; nCols = 313; bid -= 3328; }
        const int nb = (bid % nCols) * 32, kb = (bid / nCols) * 32;
        const int tx = threadIdx.x & 31, ty = threadIdx.x >> 5;
        #pragma unroll
        for (int i = ty; i < 32; i += 8) {
            int n = nb + tx;
            t[i][tx] = (n < N) ? src[(size_t)(kb + i) * N + n] : 0.f;
        }
        __syncthreads();
        #pragma unroll
        for (int i = ty; i < 32; i += 8) {
            int n = nb + i;
            if (n < N) dst[(size_t)n * K + kb + tx] = f2us(t[tx][i]);
        }
    } else if (bid < 21264) {                  // ---- mean over L ----
        bid -= 20752;
        const int b = bid >> 3;
        const int e = (bid & 7) * 256 + threadIdx.x;
        const float* p = enc + (size_t)b * NL * NENC + e;
        float s = 0.f;
        #pragma unroll 7
        for (int l = 0; l < NL; ++l) s += p[(size_t)l * NENC];
        meanbf[(size_t)b * NENC + e] = f2us(s * (1.0f / NL));
    } else {                                   // ---- zero flags ----
        if (threadIdx.x < NT) flags[threadIdx.x] = 0;
    }
}

// ---------------------------------------------------------------------------
// K_mfma2: encproj + init GEMMs in ONE launch, both 8-wave K-split-2.
//  blocks [0,392): epb(3136,512) = encb @ WeaT^T + bea (r6 tiling + K-split).
//  blocks [392,456): [h|c](64,1024) = meanbf @ WicT^T + bias.
// ---------------------------------------------------------------------------
__launch_bounds__(512)
__global__ void k_mfma2(const unsigned short* __restrict__ encb,
                        const unsigned short* __restrict__ WeaT,
                        const float* __restrict__ bea,
                        unsigned short* __restrict__ epb,
                        const unsigned short* __restrict__ meanbf,
                        const unsigned short* __restrict__ WicT,
                        const float* __restrict__ bh, const float* __restrict__ bc,
                        unsigned short* __restrict__ hbf, float* __restrict__ c)
{
    __shared__ float comb[4 * 64 * 16];   // 16 KB
    const int tid = threadIdx.x;
    const int wave = tid >> 6, lane = tid & 63;
    const int r = lane & 15, quad = lane >> 4;
    if (blockIdx.x < 392) {
        const int j = ((int)blockIdx.x & 7) * 49 + ((int)blockIdx.x >> 3);  // bijective
        const int ng = j & 7, mg = j >> 3;
        const int ow = wave & 3, kh = wave >> 2;      // output quadrant, k-half
        const int wm = ow >> 1, wn = ow & 1;
        const int m0 = mg * 64 + wm * 32;
        const int n0 = ng * 64 + wn * 32;
        const int kb = kh * (NENC / 2);
        const unsigned short* ap0 = encb + (size_t)(m0 + r) * NENC + kb + quad * 8;
        const unsigned short* ap1 = ap0 + (size_t)16 * NENC;
        const unsigned short* bp0 = WeaT + (size_t)(n0 + r) * NENC + kb + quad * 8;
        const unsigned short* bp1 = bp0 + (size_t)16 * NENC;
        f32x4 a00 = {0.f,0.f,0.f,0.f}, a01 = {0.f,0.f,0.f,0.f};
        f32x4 a10 = {0.f,0.f,0.f,0.f}, a11 = {0.f,0.f,0.f,0.f};
        #pragma unroll 4
        for (int k = 0; k < NENC / 2; k += 32) {
            bfrag x0 = *(const bfrag*)(ap0 + k);
            bfrag x1 = *(const bfrag*)(ap1 + k);
            bfrag y0 = *(const bfrag*)(bp0 + k);
            bfrag y1 = *(const bfrag*)(bp1 + k);
            a00 = __builtin_amdgcn_mfma_f32_16x16x32_bf16(x0, y0, a00, 0, 0, 0);
            a01 = __builtin_amdgcn_mfma_f32_16x16x32_bf16(x0, y1, a01, 0, 0, 0);
            a10 = __builtin_amdgcn_mfma_f32_16x16x32_bf16(x1, y0, a10, 0, 0, 0);
            a11 = __builtin_amdgcn_mfma_f32_16x16x32_bf16(x1, y1, a11, 0, 0, 0);
        }
        if (kh == 1) {
            float* d = comb + (ow * 64 + lane) * 16;
            #pragma unroll
            for (int i = 0; i < 4; ++i) {
                d[i]      = a00[i];
                d[4 + i]  = a01[i];
                d[8 + i]  = a10[i];
                d[12 + i] = a11[i];
            }
        }
        __syncthreads();
        if (kh == 0) {
            const float* d = comb + (ow * 64 + lane) * 16;
            const float bv0 = bea[n0 + r], bv1 = bea[n0 + 16 + r];
            #pragma unroll
            for (int i = 0; i < 4; ++i) {
                int ma = m0 + quad * 4 + i, mb = ma + 16;
                epb[(size_t)ma * NA + n0 + r]      = f2us(a00[i] + d[i]      + bv0);
                epb[(size_t)ma * NA + n0 + 16 + r] = f2us(a01[i] + d[4 + i]  + bv1);
                epb[(size_t)mb * NA + n0 + r]      = f2us(a10[i] + d[8 + i]  + bv0);
                epb[(size_t)mb * NA + n0 + 16 + r] = f2us(a11[i] + d[12 + i] + bv1);
            }
        }
    } else {
        // init: [h|c](64,1024) — block = one 16-col n-tile, 4 m-tiles x 2 k-halves
        const int nt = (int)blockIdx.x - 392;         // 0..63
        const int n0 = nt * 16;
        const int mtile = wave & 3, kh = wave >> 2;
        const int m0 = mtile * 16;
        const int kb = kh * (NENC / 2);
        const unsigned short* ap = meanbf + (size_t)(m0 + r) * NENC + kb + quad * 8;
        const unsigned short* bp = WicT   + (size_t)(n0 + r) * NENC + kb + quad * 8;
        f32x4 acc = {0.f, 0.f, 0.f, 0.f};
        #pragma unroll 4
        for (int k = 0; k < NENC / 2; k += 32) {
            bfrag a = *(const bfrag*)(ap + k);
            bfrag b = *(const bfrag*)(bp + k);
            acc = __builtin_amdgcn_mfma_f32_16x16x32_bf16(a, b, acc, 0, 0, 0);
        }
        if (kh == 1) {
            float* d = comb + (mtile * 64 + lane) * 4;
            #pragma unroll
            for (int i = 0; i < 4; ++i) d[i] = acc[i];
        }
        __syncthreads();
        if (kh == 0) {
            const float* d = comb + (mtile * 64 + lane) * 4;
            const int n = n0 + r;
            const bool isC = n >= ND;
            const float bv = isC ? bc[n - ND] : bh[n];
            #pragma unroll
            for (int i = 0; i < 4; ++i) {
                int m = m0 + quad * 4 + i;
                float v = acc[i] + d[i] + bv;
                if (isC) c[(size_t)m * ND + (n - ND)] = v;
                else     hbf[(size_t)m * ND + n] = f2us(v);
            }
        }
    }
}

// ---------------------------------------------------------------------------
// logits tile-tasks in [lo,hi) over workers; 8 waves = 2 task slots.
// ---------------------------------------------------------------------------
__device__ __forceinline__ void logits_tasks(int t, int lo, int hi,
    int worker, int nworkers, int wave, int lane,
    const unsigned short* hbf, const unsigned short* WoutT,
    const float* bout, float* out)
{
    const int slot = wave >> 2, w4 = wave & 3;
    const int r = lane & 15, quad = lane >> 4;
    const int m0 = w4 * 16;
    for (int task = lo + worker * 2 + slot; task < hi; task += nworkers * 2) {
        const int n0 = task * 16;                      // task < 625
        const unsigned short* ap = hbf + (size_t)(m0 + r) * ND + quad * 8;
        const unsigned short* bp = WoutT + (size_t)(n0 + r) * ND + quad * 8;
        f32x4 acc = {0.f, 0.f, 0.f, 0.f};
        #pragma unroll
        for (int k = 0; k < ND; k += 32) {
            bfrag a = *(const bfrag*)(ap + k);
            bfrag b = *(const bfrag*)(bp + k);
            acc = __builtin_amdgcn_mfma_f32_16x16x32_bf16(a, b, acc, 0, 0, 0);
        }
        const float bv = bout[n0 + r];
        #pragma unroll
        for (int i = 0; i < 4; ++i) {
            int m = m0 + quad * 4 + i;
            out[((size_t)m * NT + t) * NV + n0 + r] = acc[i] + bv;
        }
    }
}

// ---------------------------------------------------------------------------
// att body (r8 fast path) with flag-gated dp read: fill x first (no dp
// needed), then wait for the 16 producer blocks, then load dp and proceed.
// ---------------------------------------------------------------------------
__device__ __forceinline__ void att_body(int t, int b, int tid,
    const unsigned short* hcur, const float* dpg, const unsigned short* epb,
    const unsigned short* encb, const float* wf, const float* bfs,
    const float* embt, const int* caps, unsigned short* x, float* alpha_out,
    int* flags,
    float* dp /*smem 512*/, float* al /*smem 64*/)
{
    x[(size_t)b * KX + NE + NENC + tid] = hcur[(size_t)b * ND + tid];  // h tail
    const int tok = caps[b * NT + t];
    x[(size_t)b * KX + tid] = f2us(embt[(size_t)tok * NE + tid]);      // emb head

    // wait for dp producers (blocks 0..15): lane-leaders spin, then each
    // thread issues one acquire load to establish device-scope ordering.
    if ((tid & 63) == 0) {
        while (__hip_atomic_load(&flags[t], __ATOMIC_RELAXED,
                                 __HIP_MEMORY_SCOPE_AGENT) < 16)
            __builtin_amdgcn_s_sleep(2);
    }
    __syncthreads();
    (void)__hip_atomic_load(&flags[t], __ATOMIC_ACQUIRE, __HIP_MEMORY_SCOPE_AGENT);

    dp[tid] = dpg[(size_t)b * NA + tid];
    __syncthreads();

    const int wave = tid >> 6, lane = tid & 63;
    const float bfull = bfs[0];
    for (int l = wave; l < NL; l += 8) {
        const unsigned short* ep = epb + ((size_t)b * NL + l) * NA;
        float s = 0.f;
        #pragma unroll
        for (int a = lane; a < NA; a += 64) {
            float v = us2f(ep[a]) + dp[a];
            v = v > 0.f ? v : 0.f;
            s = fmaf(v, wf[a], s);
        }
        #pragma unroll
        for (int off = 32; off > 0; off >>= 1) s += __shfl_down(s, off, 64);
        if (lane == 0) al[l] = s + bfull;
    }
    __syncthreads();

    if (tid < 64) {
        float v = (tid < NL) ? al[tid] : -1e30f;
        float m = v;
        #pragma unroll
        for (int off = 32; off > 0; off >>= 1) m = fmaxf(m, __shfl_xor(m, off, 64));
        float e = (tid < NL) ? expf(v - m) : 0.f;
        float s = e;
        #pragma unroll
        for (int off = 32; off > 0; off >>= 1) s += __shfl_xor(s, off, 64);
        float a = e / s;
        if (tid < NL) {
            al[tid] = a;
            alpha_out[((size_t)b * NT + t) * NL + tid] = a;
        }
    }
    __syncthreads();

    {   // context: thread covers 4 consecutive e (512*4 = 2048), ushort4
        const int e = tid * 4;
        const unsigned short* p = encb + (size_t)b * NL * NENC + e;
        float s0 = 0.f, s1 = 0.f, s2 = 0.f, s3 = 0.f;
        #pragma unroll 7
        for (int l = 0; l < NL; ++l) {
            ushort4 v = *(const ushort4*)(p + (size_t)l * NENC);
            float a = al[l];
            s0 = fmaf(a, us2f(v.x), s0);
            s1 = fmaf(a, us2f(v.y), s1);
            s2 = fmaf(a, us2f(v.z), s2);
            s3 = fmaf(a, us2f(v.w), s3);
        }
        unsigned short* xo = x + (size_t)b * KX + NE + e;
        xo[0] = f2us(s0); xo[1] = f2us(s1); xo[2] = f2us(s2); xo[3] = f2us(s3);
    }
}

// ---------------------------------------------------------------------------
// K_att_logits: blocks 0..15 = dp producers (dedicated decproj GEMM, same
// MFMA sequence as the old k_decproj — 0.5MB WdaT read ONCE, not per-block);
// blocks 16..79 = att(t) (flag-gated); blocks 80..271 = logits(t-1) [0,384).
// Producers are the FIRST-dispatched blocks -> no scheduling deadlock even
// at 1 block/CU; at 512thr/28VGPR/4.4KB LDS all 272 blocks are co-resident.
// ---------------------------------------------------------------------------
__launch_bounds__(512)
__global__ void k_att_logits(int t,
                             const unsigned short* __restrict__ hcur,
                             float* __restrict__ dp,
                             const unsigned short* __restrict__ WdaT,
                             const float* __restrict__ bda,
                             const unsigned short* __restrict__ epb,
                             const unsigned short* __restrict__ encb,
                             const float* __restrict__ wf,
                             const float* __restrict__ bfs,
                             const float* __restrict__ embt,
                             const int* __restrict__ captions,
                             unsigned short* __restrict__ x,
                             float* __restrict__ alpha_out,
                             const unsigned short* __restrict__ WoutT,
                             const float* __restrict__ bout,
                             float* __restrict__ out,
                             int* __restrict__ flags)
{
    __shared__ float smem[576];
    const int bid = blockIdx.x, tid = threadIdx.x;
    const int wave = tid >> 6, lane = tid & 63;
    if (bid < 16) {
        // ---- dp producer: dp(64,512) = hcur @ WdaT^T + bda, 2 tiles/block
        const int slot = wave >> 2, w4 = wave & 3;
        const int tile = bid * 2 + slot;            // 0..31
        const int n0 = tile * 16, m0 = w4 * 16;
        const int r = lane & 15, quad = lane >> 4;
        const unsigned short* ap = hcur + (size_t)(m0 + r) * ND + quad * 8;
        const unsigned short* bp = WdaT + (size_t)(n0 + r) * ND + quad * 8;
        f32x4 acc = {0.f, 0.f, 0.f, 0.f};
        #pragma unroll
        for (int k = 0; k < ND; k += 32) {
            bfrag a = *(const bfrag*)(ap + k);
            bfrag b = *(const bfrag*)(bp + k);
            acc = __builtin_amdgcn_mfma_f32_16x16x32_bf16(a, b, acc, 0, 0, 0);
        }
        const float bv = bda[n0 + r];
        #pragma unroll
        for (int i = 0; i < 4; ++i) {
            int m = m0 + quad * 4 + i;
            dp[(size_t)m * NA + n0 + r] = acc[i] + bv;
        }
        __threadfence();          // make dp stores agent-visible
        __syncthreads();
        if (tid == 0)
            __hip_atomic_fetch_add(&flags[t], 1, __ATOMIC_RELEASE,
                                   __HIP_MEMORY_SCOPE_AGENT);
    } else if (bid < 80) {
        att_body(t, bid - 16, tid, hcur, dp, epb, encb, wf, bfs,
                 embt, captions, x, alpha_out, flags, smem, smem + 512);
    } else if (t > 0) {
        logits_tasks(t - 1, 0, 384, bid - 80, 192, wave, lane,
                     hcur, WoutT, bout, out);
    }
}

// ---------------------------------------------------------------------------
// K_gates_lstm: blocks 0..127 = fused gates GEMM + LSTM (8-wave K-split,
// XCD-grouped bid->(ng,mt)); parallel 256-thread epilogue. Blocks 128..248 =
// logits(t-1) tasks [384,625). h ping-pong for race-freedom.
// ---------------------------------------------------------------------------
__launch_bounds__(512)
__global__ void k_gates_lstm(int t,
                             const unsigned short* __restrict__ x,     // (64,3072)
                             const unsigned short* __restrict__ Wihb,  // (2048,2560)
                             const unsigned short* __restrict__ Whhb,  // (2048,512)
                             const float* __restrict__ bih, const float* __restrict__ bhh,
                             unsigned short* __restrict__ hnxt, float* __restrict__ c,
                             const unsigned short* __restrict__ hcur,
                             const unsigned short* __restrict__ WoutT,
                             const float* __restrict__ bout,
                             float* __restrict__ out)
{
    __shared__ float part[8 * 4 * 16 * 16];   // 32 KB
    const int bid = blockIdx.x;
    const int wave = threadIdx.x >> 6, lane = threadIdx.x & 63;
    if (bid >= 128) {
        if (t > 0)
            logits_tasks(t - 1, 384, 625, bid - 128, 121, wave, lane,
                         hcur, WoutT, bout, out);
        return;
    }
    // XCD-grouped mapping: bid%8 = ng>>2 for all 4 mt copies of an ng
    const int ng = (bid & 7) * 4 + ((bid >> 3) & 3);
    const int mt = bid >> 5;
    const int m0 = mt * 16, n0 = ng * 16;
    const int r = lane & 15, quad = lane >> 4;
    const int k0 = wave * (KX / 8), k1 = k0 + (KX / 8);   // 384-wide chunks

    const unsigned short* ap = x + (size_t)(m0 + r) * KX + quad * 8;
    const unsigned short* bpih[4];
    const unsigned short* bphh[4];
    #pragma unroll
    for (int g = 0; g < 4; ++g) {
        bpih[g] = Wihb + (size_t)(g * ND + n0 + r) * KIH + quad * 8;
        bphh[g] = Whhb + (size_t)(g * ND + n0 + r) * ND + quad * 8;
    }
    f32x4 acc[4] = {{0.f,0.f,0.f,0.f},{0.f,0.f,0.f,0.f},
                    {0.f,0.f,0.f,0.f},{0.f,0.f,0.f,0.f}};

    const int kiA = (k1 < KIH) ? k1 : KIH;
    #pragma unroll 4
    for (int k = k0; k < kiA; k += 32) {
        bfrag a = *(const bfrag*)(ap + k);
        #pragma unroll
        for (int g = 0; g < 4; ++g) {
            bfrag b = *(const bfrag*)(bpih[g] + k);
            acc[g] = __builtin_amdgcn_mfma_f32_16x16x32_bf16(a, b, acc[g], 0, 0, 0);
        }
    }
    const int kiB = (k0 > KIH) ? k0 : KIH;
    #pragma unroll 4
    for (int k = kiB; k < k1; k += 32) {
        bfrag a = *(const bfrag*)(ap + k);
        #pragma unroll
        for (int g = 0; g < 4; ++g) {
            bfrag b = *(const bfrag*)(bphh[g] + (k - KIH));
            acc[g] = __builtin_amdgcn_mfma_f32_16x16x32_bf16(a, b, acc[g], 0, 0, 0);
        }
    }

    #pragma unroll
    for (int g = 0; g < 4; ++g)
        #pragma unroll
        for (int i = 0; i < 4; ++i)
            part[((wave * 4 + g) * 16 + quad * 4 + i) * 16 + r] = acc[g][i];
    __syncthreads();

    if (threadIdx.x < 256) {
        const int row = threadIdx.x >> 4, col = threadIdx.x & 15;
        float gs[4];
        #pragma unroll
        for (int g = 0; g < 4; ++g) {
            float v = 0.f;
            #pragma unroll
            for (int w = 0; w < 8; ++w)
                v += part[((w * 4 + g) * 16 + row) * 16 + col];
            gs[g] = v;
        }
        const int d = n0 + col;
        const int m = m0 + row;
        float gi = gs[0] + bih[d]        + bhh[d];
        float gf = gs[1] + bih[d + 512]  + bhh[d + 512];
        float gg = gs[2] + bih[d + 1024] + bhh[d + 1024];
        float go = gs[3] + bih[d + 1536] + bhh[d + 1536];
        float ig = 1.f / (1.f + expf(-gi));
        float fg = 1.f / (1.f + expf(-gf));
        float g  = tanhf(gg);
        float og = 1.f / (1.f + expf(-go));
        float cn = fg * c[(size_t)m * ND + d] + ig * g;
        float hn = og * tanhf(cn);
        c[(size_t)m * ND + d] = cn;
        hnxt[(size_t)m * ND + d] = f2us(hn);
    }
}

// ---------------------------------------------------------------------------
// K_logits_fin: full logits for the last step. grid 313 x 512.
// ---------------------------------------------------------------------------
__launch_bounds__(512)
__global__ void k_logits_fin(int t,
                             const unsigned short* __restrict__ hbf,
                             const unsigned short* __restrict__ WoutT,
                             const float* __restrict__ bout,
                             float* __restrict__ out)
{
    logits_tasks(t, 0, 625, blockIdx.x, 313, threadIdx.x >> 6, threadIdx.x & 63,
                 hbf, WoutT, bout, out);
}

// ---------------------------------------------------------------------------
extern "C" void kernel_launch(void* const* d_in, const int* in_sizes, int n_in,
                              void* d_out, int out_size, void* d_ws, size_t ws_size,
                              hipStream_t stream) {
    const float* enc  = (const float*)d_in[0];
    const int*   caps = (const int*)d_in[1];
    const float* embt = (const float*)d_in[2];
    const float* Wea  = (const float*)d_in[3];
    const float* bea  = (const float*)d_in[4];
    const float* Wda  = (const float*)d_in[5];
    const float* bda  = (const float*)d_in[6];
    const float* wf   = (const float*)d_in[7];
    const float* bfs  = (const float*)d_in[8];
    const float* Wih  = (const float*)d_in[9];
    const float* bih  = (const float*)d_in[10];
    const float* Whh  = (const float*)d_in[11];
    const float* bhh  = (const float*)d_in[12];
    const float* Wh0  = (const float*)d_in[13];
    const float* bh0  = (const float*)d_in[14];
    const float* Wc0  = (const float*)d_in[15];
    const float* bc0  = (const float*)d_in[16];
    const float* Wout = (const float*)d_in[17];
    const float* bout = (const float*)d_in[18];

    float* out = (float*)d_out;                       // logits (B,T,V) f32
    float* alpha_out = out + (size_t)NB * NT * NV;    // alphas (B,T,L) f32

    // ---- workspace carve-up (16B aligned throughout) ----
    char* w = (char*)d_ws;
    float* c     = (float*)w;                 w += (size_t)NB * ND * 4;          // 128 KB
    float* dp    = (float*)w;                 w += (size_t)NB * NA * 4;          // 128 KB
    unsigned short* meanbf = (unsigned short*)w; w += (size_t)NB * NENC * 2;     // 256 KB
    unsigned short* hb    = (unsigned short*)w; w += (size_t)2 * NB * ND * 2;    // 128 KB (ping-pong)
    unsigned short* x     = (unsigned short*)w; w += (size_t)NB * KX * 2;        // 384 KB
    unsigned short* epb   = (unsigned short*)w; w += (size_t)NB * NL * NA * 2;   // 3.2 MB
    unsigned short* encb  = (unsigned short*)w; w += (size_t)NB * NL * NENC * 2; // 12.8 MB
    unsigned short* Wihb  = (unsigned short*)w; w += (size_t)4 * ND * KIH * 2;   // 10.5 MB
    unsigned short* Whhb  = (unsigned short*)w; w += (size_t)4 * ND * ND * 2;    // 2 MB
    unsigned short* WeaT  = (unsigned short*)w; w += (size_t)NA * NENC * 2;      // 2 MB
    unsigned short* WdaT  = (unsigned short*)w; w += (size_t)NA * ND * 2;        // 0.5 MB
    unsigned short* WoutT = (unsigned short*)w; w += (size_t)NV * ND * 2;        // 10.2 MB
    unsigned short* WicT  = (unsigned short*)w; w += (size_t)2 * ND * NENC * 2;  // 4 MB
    int* flags = (int*)w;                     w += 64;                           // 20 ints

    // ---- one-time setup (2 dispatches) ----
    hipLaunchKernelGGL(k_prep, dim3(21265), dim3(256), 0, stream,
                       enc, encb, Wih, Wihb, Whh, Whhb,
                       Wh0, Wc0, Wea, Wda, Wout, WicT, WeaT, WdaT, WoutT,
                       meanbf, flags);
    hipLaunchKernelGGL(k_mfma2, dim3(456), dim3(512), 0, stream,
                       encb, WeaT, bea, epb, meanbf, WicT, bh0, bc0, hb, c);

    // ---- 20 sequential decoder steps, 2 dispatches each ----
    for (int t = 0; t < NT; ++t) {
        unsigned short* hcur = hb + (size_t)(t & 1) * NB * ND;
        unsigned short* hnxt = hb + (size_t)((t + 1) & 1) * NB * ND;
        hipLaunchKernelGGL(k_att_logits, dim3(272), dim3(512), 0, stream,
                           t, hcur, dp, WdaT, bda, epb, encb, wf, bfs, embt, caps,
                           x, alpha_out, WoutT, bout, out, flags);
        hipLaunchKernelGGL(k_gates_lstm, dim3(249), dim3(512), 0, stream,
                           t, x, Wihb, Whhb, bih, bhh, hnxt, c,
                           hcur, WoutT, bout, out);
    }
    // logits for the last step (h_20 lives in hb[(NT)&1] = hb[0])
    hipLaunchKernelGGL(k_logits_fin, dim3(313), dim3(512), 0, stream,
                       NT - 1, hb + (size_t)(NT & 1) * NB * ND, WoutT, bout, out);
}

// Round 11
// 933.035 us; speedup vs baseline: 1.2342x; 1.2299x over previous
//
#include <hip/hip_runtime.h>
#include <hip/hip_bf16.h>

// Problem dims
constexpr int NV   = 10000;  // vocab
constexpr int NE   = 512;    // embed
constexpr int NENC = 2048;   // encoder dim
constexpr int ND   = 512;    // decoder dim
constexpr int NA   = 512;    // attention dim
constexpr int NB   = 64;     // batch
constexpr int NL   = 49;     // locations
constexpr int NT   = 20;     // steps
constexpr int KX   = NE + NENC + ND;  // 3072
constexpr int KIH  = NE + NENC;       // 2560 : W_ih inner dim

typedef short bfrag __attribute__((ext_vector_type(8)));   // 8 bf16 (4 VGPRs)
typedef float f32x4 __attribute__((ext_vector_type(4)));   // MFMA acc

__device__ __forceinline__ float us2f(unsigned short u) {
    union { unsigned int i; float f; } x; x.i = (unsigned int)u << 16; return x.f;
}
__device__ __forceinline__ unsigned short f2us(float f) {  // RNE f32->bf16
    union { float f_; unsigned int u; } x; x.f_ = f;
    unsigned int r = (x.u + 0x7fffu + ((x.u >> 16) & 1u)) >> 16;
    return (unsigned short)r;
}

// ---------------------------------------------------------------------------
// K_prep: all one-time data prep in ONE launch (block-range dispatch):
//   [0,6272)        enc  f32 -> encb bf16   (1024 elems/block)
//   [6272,11392)    Wih  f32 -> Wihb bf16
//   [11392,12416)   Whh  f32 -> Whhb bf16
//   [12416,20752)   5 transposes (Wh0,Wc0,Wea,Wda,Wout -> bf16 T)
//   [20752,21264)   mean over L -> meanbf bf16 (8 blocks/b)
//   [21264,22544)   emb gather: embs[t][b][:] = bf16(embt[caps[b,t]])
// ---------------------------------------------------------------------------
__launch_bounds__(256)
__global__ void k_prep(const float* __restrict__ enc, unsigned short* __restrict__ encb,
                       const float* __restrict__ Wih, unsigned short* __restrict__ Wihb,
                       const float* __restrict__ Whh, unsigned short* __restrict__ Whhb,
                       const float* __restrict__ Wh0, const float* __restrict__ Wc0,
                       const float* __restrict__ Wea, const float* __restrict__ Wda,
                       const float* __restrict__ Wout,
                       unsigned short* __restrict__ WicT, unsigned short* __restrict__ WeaT,
                       unsigned short* __restrict__ WdaT, unsigned short* __restrict__ WoutT,
                       unsigned short* __restrict__ meanbf,
                       const float* __restrict__ embt, const int* __restrict__ caps,
                       unsigned short* __restrict__ embs)
{
    int bid = blockIdx.x;
    if (bid < 12416) {                         // ---- cvt f32->bf16 ----
        const float* src; unsigned short* dst;
        if (bid < 6272)       { src = enc; dst = encb; }
        else if (bid < 11392) { src = Wih; dst = Wihb; bid -= 6272; }
        else                  { src = Whh; dst = Whhb; bid -= 11392; }
        const int i = bid * 1024 + threadIdx.x * 4;
        float4 v = *(const float4*)(src + i);
        dst[i + 0] = f2us(v.x); dst[i + 1] = f2us(v.y);
        dst[i + 2] = f2us(v.z); dst[i + 3] = f2us(v.w);
    } else if (bid < 20752) {                  // ---- transposes ----
        bid -= 12416;
        __shared__ float t[32][33];
        const float* src; unsigned short* dst; int K, N, nCols;
        if (bid < 1024)      { src = Wh0;  dst = WicT;                     K = NENC; N = ND; nCols = 16; }
        else if (bid < 2048) { src = Wc0;  dst = WicT + (size_t)ND * NENC; K = NENC; N = ND; nCols = 16; bid -= 1024; }
        else if (bid < 3072) { src = Wea;  dst = WeaT;                     K = NENC; N = NA; nCols = 16; bid -= 2048; }
        else if (bid < 3328) { src = Wda;  dst = WdaT;                     K = ND;   N = NA; nCols = 16; bid -= 3072; }
        else                 { src = Wout; dst = WoutT;                    K = ND;   N = NV; nCols = 313; bid -= 3328; }
        const int nb = (bid % nCols) * 32, kb = (bid / nCols) * 32;
        const int tx = threadIdx.x & 31, ty = threadIdx.x >> 5;
        #pragma unroll
        for (int i = ty; i < 32; i += 8) {
            int n = nb + tx;
            t[i][tx] = (n < N) ? src[(size_t)(kb + i) * N + n] : 0.f;
        }
        __syncthreads();
        #pragma unroll
        for (int i = ty; i < 32; i += 8) {
            int n = nb + i;
            if (n < N) dst[(size_t)n * K + kb + tx] = f2us(t[tx][i]);
        }
    } else if (bid < 21264) {                  // ---- mean over L ----
        bid -= 20752;
        const int b = bid >> 3;
        const int e = (bid & 7) * 256 + threadIdx.x;
        const float* p = enc + (size_t)b * NL * NENC + e;
        float s = 0.f;
        #pragma unroll 7
        for (int l = 0; l < NL; ++l) s += p[(size_t)l * NENC];
        meanbf[(size_t)b * NENC + e] = f2us(s * (1.0f / NL));
    } else {                                   // ---- emb gather ----
        bid -= 21264;
        const int t = bid >> 6, b = bid & 63;
        const int tok = caps[b * NT + t];
        float2 v = *(const float2*)(embt + (size_t)tok * NE + threadIdx.x * 2);
        unsigned short* d = embs + ((size_t)t * NB + b) * NE + threadIdx.x * 2;
        d[0] = f2us(v.x); d[1] = f2us(v.y);
    }
}

// ---------------------------------------------------------------------------
// K_mfma2: encproj + init GEMMs in ONE launch.
//  blocks [0,392): epb(3136,512) = encb @ WeaT^T + bea.
//    LDS-staged, double-buffered (issue-early/write-late reg staging),
//    BM=BN=BK=64, 8 waves = 4 output quadrants x 2 K-halves, row pad +8
//    shorts (stride 144B -> minimal-phase ds_read_b128). Dedups the 2x
//    A/B re-read of the direct-fragment scheme (r6-r10: pinned at 61us).
//  blocks [392,456): [h|c](64,1024) = meanbf @ WicT^T + bias (r8 K-split).
// ---------------------------------------------------------------------------
__launch_bounds__(512)
__global__ void k_mfma2(const unsigned short* __restrict__ encb,
                        const unsigned short* __restrict__ WeaT,
                        const float* __restrict__ bea,
                        unsigned short* __restrict__ epb,
                        const unsigned short* __restrict__ meanbf,
                        const unsigned short* __restrict__ WicT,
                        const float* __restrict__ bh, const float* __restrict__ bc,
                        unsigned short* __restrict__ hbf, float* __restrict__ c)
{
    __shared__ short lds_s[2][2][64 * 72];    // 36,864 B  [buf][A|B][row*72+col]
    float* comb = (float*)lds_s;              // alias for combine phases (16 KB)
    const int tid = threadIdx.x;
    const int wave = tid >> 6, lane = tid & 63;
    const int r = lane & 15, quad = lane >> 4;

    if (blockIdx.x < 392) {
        const int j = ((int)blockIdx.x & 7) * 49 + ((int)blockIdx.x >> 3);  // bijective
        const int ng = j & 7, mg = j >> 3;
        const int m0 = mg * 64, n0 = ng * 64;
        const int ow = wave & 3, kh = wave >> 2;
        const int wm = ow >> 1, wn = ow & 1;

        // staging coords: thread -> (row 0..63, 16B-block 0..7), coalesced
        const int grow = tid >> 3, gcb = tid & 7;
        const unsigned short* gA = encb + (size_t)(m0 + grow) * NENC + gcb * 8;
        const unsigned short* gB = WeaT + (size_t)(n0 + grow) * NENC + gcb * 8;
        const int lidx = grow * 72 + gcb * 8;

        bfrag rA = *(const bfrag*)(gA);       // K-step 0
        bfrag rB = *(const bfrag*)(gB);
        *(bfrag*)&lds_s[0][0][lidx] = rA;
        *(bfrag*)&lds_s[0][1][lidx] = rB;
        rA = *(const bfrag*)(gA + 64);        // K-step 1 into regs
        rB = *(const bfrag*)(gB + 64);
        __syncthreads();

        f32x4 a00 = {0.f,0.f,0.f,0.f}, a01 = {0.f,0.f,0.f,0.f};
        f32x4 a10 = {0.f,0.f,0.f,0.f}, a11 = {0.f,0.f,0.f,0.f};
        const int la0 = (wm * 32 + r) * 72 + kh * 32 + quad * 8;
        const int la1 = la0 + 16 * 72;
        const int lb0 = (wn * 32 + r) * 72 + kh * 32 + quad * 8;
        const int lb1 = lb0 + 16 * 72;

        #pragma unroll 2
        for (int s = 0; s < 32; ++s) {
            const int buf = s & 1;
            if (s + 1 < 32) {                 // write-late: regs(s+1) -> other buf
                *(bfrag*)&lds_s[buf ^ 1][0][lidx] = rA;
                *(bfrag*)&lds_s[buf ^ 1][1][lidx] = rB;
            }
            if (s + 2 < 32) {                 // issue-early: loads for s+2
                rA = *(const bfrag*)(gA + (s + 2) * 64);
                rB = *(const bfrag*)(gB + (s + 2) * 64);
            }
            bfrag x0 = *(const bfrag*)&lds_s[buf][0][la0];
            bfrag x1 = *(const bfrag*)&lds_s[buf][0][la1];
            bfrag y0 = *(const bfrag*)&lds_s[buf][1][lb0];
            bfrag y1 = *(const bfrag*)&lds_s[buf][1][lb1];
            a00 = __builtin_amdgcn_mfma_f32_16x16x32_bf16(x0, y0, a00, 0, 0, 0);
            a01 = __builtin_amdgcn_mfma_f32_16x16x32_bf16(x0, y1, a01, 0, 0, 0);
            a10 = __builtin_amdgcn_mfma_f32_16x16x32_bf16(x1, y0, a10, 0, 0, 0);
            a11 = __builtin_amdgcn_mfma_f32_16x16x32_bf16(x1, y1, a11, 0, 0, 0);
            __syncthreads();
        }

        // combine K-halves (kh=1 -> LDS, kh=0 adds) then epilogue
        if (kh == 1) {
            float* d = comb + (ow * 64 + lane) * 16;
            #pragma unroll
            for (int i = 0; i < 4; ++i) {
                d[i]      = a00[i];
                d[4 + i]  = a01[i];
                d[8 + i]  = a10[i];
                d[12 + i] = a11[i];
            }
        }
        __syncthreads();
        if (kh == 0) {
            const float* d = comb + (ow * 64 + lane) * 16;
            const int nb0 = n0 + wn * 32;
            const float bv0 = bea[nb0 + r], bv1 = bea[nb0 + 16 + r];
            #pragma unroll
            for (int i = 0; i < 4; ++i) {
                int ma = m0 + wm * 32 + quad * 4 + i, mb = ma + 16;
                epb[(size_t)ma * NA + nb0 + r]      = f2us(a00[i] + d[i]      + bv0);
                epb[(size_t)ma * NA + nb0 + 16 + r] = f2us(a01[i] + d[4 + i]  + bv1);
                epb[(size_t)mb * NA + nb0 + r]      = f2us(a10[i] + d[8 + i]  + bv0);
                epb[(size_t)mb * NA + nb0 + 16 + r] = f2us(a11[i] + d[12 + i] + bv1);
            }
        }
    } else {
        // init: [h|c](64,1024) — block = one 16-col n-tile, 4 m-tiles x 2 k-halves
        const int nt = (int)blockIdx.x - 392;         // 0..63
        const int n0 = nt * 16;
        const int mtile = wave & 3, kh = wave >> 2;
        const int m0 = mtile * 16;
        const int kb = kh * (NENC / 2);
        const unsigned short* ap = meanbf + (size_t)(m0 + r) * NENC + kb + quad * 8;
        const unsigned short* bp = WicT   + (size_t)(n0 + r) * NENC + kb + quad * 8;
        f32x4 acc = {0.f, 0.f, 0.f, 0.f};
        #pragma unroll 4
        for (int k = 0; k < NENC / 2; k += 32) {
            bfrag a = *(const bfrag*)(ap + k);
            bfrag b = *(const bfrag*)(bp + k);
            acc = __builtin_amdgcn_mfma_f32_16x16x32_bf16(a, b, acc, 0, 0, 0);
        }
        if (kh == 1) {
            float* d = comb + (mtile * 64 + lane) * 4;
            #pragma unroll
            for (int i = 0; i < 4; ++i) d[i] = acc[i];
        }
        __syncthreads();
        if (kh == 0) {
            const float* d = comb + (mtile * 64 + lane) * 4;
            const int n = n0 + r;
            const bool isC = n >= ND;
            const float bv = isC ? bc[n - ND] : bh[n];
            #pragma unroll
            for (int i = 0; i < 4; ++i) {
                int m = m0 + quad * 4 + i;
                float v = acc[i] + d[i] + bv;
                if (isC) c[(size_t)m * ND + (n - ND)] = v;
                else     hbf[(size_t)m * ND + n] = f2us(v);
            }
        }
    }
}

// ---------------------------------------------------------------------------
// logits tile-tasks in [lo,hi) over workers; 8 waves = 2 task slots.
// ---------------------------------------------------------------------------
__device__ __forceinline__ void logits_tasks(int t, int lo, int hi,
    int worker, int nworkers, int wave, int lane,
    const unsigned short* hbf, const unsigned short* WoutT,
    const float* bout, float* out)
{
    const int slot = wave >> 2, w4 = wave & 3;
    const int r = lane & 15, quad = lane >> 4;
    const int m0 = w4 * 16;
    for (int task = lo + worker * 2 + slot; task < hi; task += nworkers * 2) {
        const int n0 = task * 16;                      // task < 625
        const unsigned short* ap = hbf + (size_t)(m0 + r) * ND + quad * 8;
        const unsigned short* bp = WoutT + (size_t)(n0 + r) * ND + quad * 8;
        f32x4 acc = {0.f, 0.f, 0.f, 0.f};
        #pragma unroll
        for (int k = 0; k < ND; k += 32) {
            bfrag a = *(const bfrag*)(ap + k);
            bfrag b = *(const bfrag*)(bp + k);
            acc = __builtin_amdgcn_mfma_f32_16x16x32_bf16(a, b, acc, 0, 0, 0);
        }
        const float bv = bout[n0 + r];
        #pragma unroll
        for (int i = 0; i < 4; ++i) {
            int m = m0 + quad * 4 + i;
            out[((size_t)m * NT + t) * NV + n0 + r] = acc[i] + bv;
        }
    }
}

// ---------------------------------------------------------------------------
// att body: one 512-thread block per b, dp from workspace, ushort4 context.
// x-assembly removed: emb precomputed (embs), h read directly by gates —
// att only writes ctx.
// ---------------------------------------------------------------------------
__device__ __forceinline__ void att_body(int t, int b, int tid,
    const float* dpg, const unsigned short* epb, const unsigned short* encb,
    const float* wf, const float* bfs, unsigned short* ctx, float* alpha_out,
    float* dp /*smem 512*/, float* al /*smem 64*/)
{
    dp[tid] = dpg[(size_t)b * NA + tid];
    __syncthreads();

    const int wave = tid >> 6, lane = tid & 63;
    const float bfull = bfs[0];
    for (int l = wave; l < NL; l += 8) {
        const unsigned short* ep = epb + ((size_t)b * NL + l) * NA;
        float s = 0.f;
        #pragma unroll
        for (int a = lane; a < NA; a += 64) {
            float v = us2f(ep[a]) + dp[a];
            v = v > 0.f ? v : 0.f;
            s = fmaf(v, wf[a], s);
        }
        #pragma unroll
        for (int off = 32; off > 0; off >>= 1) s += __shfl_down(s, off, 64);
        if (lane == 0) al[l] = s + bfull;
    }
    __syncthreads();

    if (tid < 64) {
        float v = (tid < NL) ? al[tid] : -1e30f;
        float m = v;
        #pragma unroll
        for (int off = 32; off > 0; off >>= 1) m = fmaxf(m, __shfl_xor(m, off, 64));
        float e = (tid < NL) ? expf(v - m) : 0.f;
        float s = e;
        #pragma unroll
        for (int off = 32; off > 0; off >>= 1) s += __shfl_xor(s, off, 64);
        float a = e / s;
        if (tid < NL) {
            al[tid] = a;
            alpha_out[((size_t)b * NT + t) * NL + tid] = a;
        }
    }
    __syncthreads();

    {   // context: thread covers 4 consecutive e (512*4 = 2048), ushort4
        const int e = tid * 4;
        const unsigned short* p = encb + (size_t)b * NL * NENC + e;
        float s0 = 0.f, s1 = 0.f, s2 = 0.f, s3 = 0.f;
        #pragma unroll 7
        for (int l = 0; l < NL; ++l) {
            ushort4 v = *(const ushort4*)(p + (size_t)l * NENC);
            float a = al[l];
            s0 = fmaf(a, us2f(v.x), s0);
            s1 = fmaf(a, us2f(v.y), s1);
            s2 = fmaf(a, us2f(v.z), s2);
            s3 = fmaf(a, us2f(v.w), s3);
        }
        unsigned short* xo = ctx + (size_t)b * NENC + e;
        xo[0] = f2us(s0); xo[1] = f2us(s1); xo[2] = f2us(s2); xo[3] = f2us(s3);
    }
}

// ---------------------------------------------------------------------------
// K_att_logits: blocks 0..63 = att(t); blocks 64..255 = logits(t-1) tasks
// [0,384) over 192 workers. Grid 256 = 1 block/CU. Read-only on hcur.
// ---------------------------------------------------------------------------
__launch_bounds__(512)
__global__ void k_att_logits(int t,
                             const unsigned short* __restrict__ hcur,
                             const float* __restrict__ dpg,
                             const unsigned short* __restrict__ epb,
                             const unsigned short* __restrict__ encb,
                             const float* __restrict__ wf,
                             const float* __restrict__ bfs,
                             unsigned short* __restrict__ ctx,
                             float* __restrict__ alpha_out,
                             const unsigned short* __restrict__ WoutT,
                             const float* __restrict__ bout,
                             float* __restrict__ out)
{
    __shared__ float smem[576];
    const int bid = blockIdx.x, tid = threadIdx.x;
    if (bid < 64) {
        att_body(t, bid, tid, dpg, epb, encb, wf, bfs, ctx, alpha_out,
                 smem, smem + 512);
    } else if (t > 0) {
        logits_tasks(t - 1, 0, 384, bid - 64, 192, tid >> 6, tid & 63,
                     hcur, WoutT, bout, out);
    }
}

// ---------------------------------------------------------------------------
// K_gates_lstm: blocks 0..127 = fused gates GEMM + LSTM (8-wave K-split,
// XCD-grouped bid->(ng,mt)); A read from three bases (embs | ctx | hcur) —
// 16B chunks never straddle the 512/2560 boundaries. Parallel 256-thread
// epilogue. Blocks 128..248 = logits(t-1) tasks [384,625). h ping-pong.
// ---------------------------------------------------------------------------
__launch_bounds__(512)
__global__ void k_gates_lstm(int t,
                             const unsigned short* __restrict__ embs,  // (T,B,512)
                             const unsigned short* __restrict__ ctx,   // (B,2048)
                             const unsigned short* __restrict__ Wihb,  // (2048,2560)
                             const unsigned short* __restrict__ Whhb,  // (2048,512)
                             const float* __restrict__ bih, const float* __restrict__ bhh,
                             unsigned short* __restrict__ hnxt, float* __restrict__ c,
                             const unsigned short* __restrict__ hcur,
                             const unsigned short* __restrict__ WoutT,
                             const float* __restrict__ bout,
                             float* __restrict__ out)
{
    __shared__ float part[8 * 4 * 16 * 16];   // 32 KB
    const int bid = blockIdx.x;
    const int wave = threadIdx.x >> 6, lane = threadIdx.x & 63;
    if (bid >= 128) {
        if (t > 0)
            logits_tasks(t - 1, 384, 625, bid - 128, 121, wave, lane,
                         hcur, WoutT, bout, out);
        return;
    }
    // XCD-grouped mapping: bid%8 = ng>>2 for all 4 mt copies of an ng
    const int ng = (bid & 7) * 4 + ((bid >> 3) & 3);
    const int mt = bid >> 5;
    const int m0 = mt * 16, n0 = ng * 16;
    const int r = lane & 15, quad = lane >> 4;
    const int k0 = wave * (KX / 8), k1 = k0 + (KX / 8);   // 384-wide chunks

    const int arow = m0 + r;
    const unsigned short* aE = embs + ((size_t)t * NB + arow) * NE + quad * 8;
    const unsigned short* aC = ctx + (size_t)arow * NENC + quad * 8;
    const unsigned short* aH = hcur + (size_t)arow * ND + quad * 8;
    const unsigned short* bpih[4];
    const unsigned short* bphh[4];
    #pragma unroll
    for (int g = 0; g < 4; ++g) {
        bpih[g] = Wihb + (size_t)(g * ND + n0 + r) * KIH + quad * 8;
        bphh[g] = Whhb + (size_t)(g * ND + n0 + r) * ND + quad * 8;
    }
    f32x4 acc[4] = {{0.f,0.f,0.f,0.f},{0.f,0.f,0.f,0.f},
                    {0.f,0.f,0.f,0.f},{0.f,0.f,0.f,0.f}};

    const int kiA = (k1 < KIH) ? k1 : KIH;
    #pragma unroll 4
    for (int k = k0; k < kiA; k += 32) {
        bfrag a = (k < NE) ? *(const bfrag*)(aE + k)
                           : *(const bfrag*)(aC + (k - NE));
        #pragma unroll
        for (int g = 0; g < 4; ++g) {
            bfrag b = *(const bfrag*)(bpih[g] + k);
            acc[g] = __builtin_amdgcn_mfma_f32_16x16x32_bf16(a, b, acc[g], 0, 0, 0);
        }
    }
    const int kiB = (k0 > KIH) ? k0 : KIH;
    #pragma unroll 4
    for (int k = kiB; k < k1; k += 32) {
        bfrag a = *(const bfrag*)(aH + (k - KIH));
        #pragma unroll
        for (int g = 0; g < 4; ++g) {
            bfrag b = *(const bfrag*)(bphh[g] + (k - KIH));
            acc[g] = __builtin_amdgcn_mfma_f32_16x16x32_bf16(a, b, acc[g], 0, 0, 0);
        }
    }

    #pragma unroll
    for (int g = 0; g < 4; ++g)
        #pragma unroll
        for (int i = 0; i < 4; ++i)
            part[((wave * 4 + g) * 16 + quad * 4 + i) * 16 + r] = acc[g][i];
    __syncthreads();

    if (threadIdx.x < 256) {
        const int row = threadIdx.x >> 4, col = threadIdx.x & 15;
        float gs[4];
        #pragma unroll
        for (int g = 0; g < 4; ++g) {
            float v = 0.f;
            #pragma unroll
            for (int w = 0; w < 8; ++w)
                v += part[((w * 4 + g) * 16 + row) * 16 + col];
            gs[g] = v;
        }
        const int d = n0 + col;
        const int m = m0 + row;
        float gi = gs[0] + bih[d]        + bhh[d];
        float gf = gs[1] + bih[d + 512]  + bhh[d + 512];
        float gg = gs[2] + bih[d + 1024] + bhh[d + 1024];
        float go = gs[3] + bih[d + 1536] + bhh[d + 1536];
        float ig = 1.f / (1.f + expf(-gi));
        float fg = 1.f / (1.f + expf(-gf));
        float g  = tanhf(gg);
        float og = 1.f / (1.f + expf(-go));
        float cn = fg * c[(size_t)m * ND + d] + ig * g;
        float hn = og * tanhf(cn);
        c[(size_t)m * ND + d] = cn;
        hnxt[(size_t)m * ND + d] = f2us(hn);
    }
}

// ---------------------------------------------------------------------------
// K_decproj: dp(64,512) = hbf @ WdaT^T + bda. grid 16 x 512 (2 tiles/block).
// ---------------------------------------------------------------------------
__launch_bounds__(512)
__global__ void k_decproj(const unsigned short* __restrict__ hbf,
                          const unsigned short* __restrict__ WdaT,
                          const float* __restrict__ bda, float* __restrict__ dp)
{
    const int wave = threadIdx.x >> 6, lane = threadIdx.x & 63;
    const int slot = wave >> 2, w4 = wave & 3;
    const int tile = blockIdx.x * 2 + slot;            // 0..31
    const int n0 = tile * 16, m0 = w4 * 16;
    const int r = lane & 15, quad = lane >> 4;
    const unsigned short* ap = hbf + (size_t)(m0 + r) * ND + quad * 8;
    const unsigned short* bp = WdaT + (size_t)(n0 + r) * ND + quad * 8;
    f32x4 acc = {0.f, 0.f, 0.f, 0.f};
    #pragma unroll
    for (int k = 0; k < ND; k += 32) {
        bfrag a = *(const bfrag*)(ap + k);
        bfrag b = *(const bfrag*)(bp + k);
        acc = __builtin_amdgcn_mfma_f32_16x16x32_bf16(a, b, acc, 0, 0, 0);
    }
    const float bv = bda[n0 + r];
    #pragma unroll
    for (int i = 0; i < 4; ++i) {
        int m = m0 + quad * 4 + i;
        dp[(size_t)m * NA + n0 + r] = acc[i] + bv;
    }
}

// ---------------------------------------------------------------------------
// K_logits_fin: full logits for the last step. grid 313 x 512.
// ---------------------------------------------------------------------------
__launch_bounds__(512)
__global__ void k_logits_fin(int t,
                             const unsigned short* __restrict__ hbf,
                             const unsigned short* __restrict__ WoutT,
                             const float* __restrict__ bout,
                             float* __restrict__ out)
{
    logits_tasks(t, 0, 625, blockIdx.x, 313, threadIdx.x >> 6, threadIdx.x & 63,
                 hbf, WoutT, bout, out);
}

// ---------------------------------------------------------------------------
extern "C" void kernel_launch(void* const* d_in, const int* in_sizes, int n_in,
                              void* d_out, int out_size, void* d_ws, size_t ws_size,
                              hipStream_t stream) {
    const float* enc  = (const float*)d_in[0];
    const int*   caps = (const int*)d_in[1];
    const float* embt = (const float*)d_in[2];
    const float* Wea  = (const float*)d_in[3];
    const float* bea  = (const float*)d_in[4];
    const float* Wda  = (const float*)d_in[5];
    const float* bda  = (const float*)d_in[6];
    const float* wf   = (const float*)d_in[7];
    const float* bfs  = (const float*)d_in[8];
    const float* Wih  = (const float*)d_in[9];
    const float* bih  = (const float*)d_in[10];
    const float* Whh  = (const float*)d_in[11];
    const float* bhh  = (const float*)d_in[12];
    const float* Wh0  = (const float*)d_in[13];
    const float* bh0  = (const float*)d_in[14];
    const float* Wc0  = (const float*)d_in[15];
    const float* bc0  = (const float*)d_in[16];
    const float* Wout = (const float*)d_in[17];
    const float* bout = (const float*)d_in[18];

    float* out = (float*)d_out;                       // logits (B,T,V) f32
    float* alpha_out = out + (size_t)NB * NT * NV;    // alphas (B,T,L) f32

    // ---- workspace carve-up (16B aligned throughout) ----
    char* w = (char*)d_ws;
    float* c     = (float*)w;                 w += (size_t)NB * ND * 4;          // 128 KB
    float* dp    = (float*)w;                 w += (size_t)NB * NA * 4;          // 128 KB
    unsigned short* meanbf = (unsigned short*)w; w += (size_t)NB * NENC * 2;     // 256 KB
    unsigned short* hb    = (unsigned short*)w; w += (size_t)2 * NB * ND * 2;    // 128 KB (ping-pong)
    unsigned short* ctx   = (unsigned short*)w; w += (size_t)NB * NENC * 2;      // 256 KB
    unsigned short* embs  = (unsigned short*)w; w += (size_t)NT * NB * NE * 2;   // 1.31 MB
    unsigned short* epb   = (unsigned short*)w; w += (size_t)NB * NL * NA * 2;   // 3.2 MB
    unsigned short* encb  = (unsigned short*)w; w += (size_t)NB * NL * NENC * 2; // 12.8 MB
    unsigned short* Wihb  = (unsigned short*)w; w += (size_t)4 * ND * KIH * 2;   // 10.5 MB
    unsigned short* Whhb  = (unsigned short*)w; w += (size_t)4 * ND * ND * 2;    // 2 MB
    unsigned short* WeaT  = (unsigned short*)w; w += (size_t)NA * NENC * 2;      // 2 MB
    unsigned short* WdaT  = (unsigned short*)w; w += (size_t)NA * ND * 2;        // 0.5 MB
    unsigned short* WoutT = (unsigned short*)w; w += (size_t)NV * ND * 2;        // 10.2 MB
    unsigned short* WicT  = (unsigned short*)w; w += (size_t)2 * ND * NENC * 2;  // 4 MB

    // ---- one-time setup (2 dispatches) ----
    hipLaunchKernelGGL(k_prep, dim3(22544), dim3(256), 0, stream,
                       enc, encb, Wih, Wihb, Whh, Whhb,
                       Wh0, Wc0, Wea, Wda, Wout, WicT, WeaT, WdaT, WoutT,
                       meanbf, embt, caps, embs);
    hipLaunchKernelGGL(k_mfma2, dim3(456), dim3(512), 0, stream,
                       encb, WeaT, bea, epb, meanbf, WicT, bh0, bc0, hb, c);
    // dp(0) from h_init
    hipLaunchKernelGGL(k_decproj, dim3(16), dim3(512), 0, stream, hb, WdaT, bda, dp);

    // ---- 20 sequential decoder steps, 3 dispatches each ----
    for (int t = 0; t < NT; ++t) {
        unsigned short* hcur = hb + (size_t)(t & 1) * NB * ND;
        unsigned short* hnxt = hb + (size_t)((t + 1) & 1) * NB * ND;
        hipLaunchKernelGGL(k_att_logits, dim3(256), dim3(512), 0, stream,
                           t, hcur, dp, epb, encb, wf, bfs, ctx, alpha_out,
                           WoutT, bout, out);
        hipLaunchKernelGGL(k_gates_lstm, dim3(249), dim3(512), 0, stream,
                           t, embs, ctx, Wihb, Whhb, bih, bhh, hnxt, c,
                           hcur, WoutT, bout, out);
        if (t + 1 < NT)
            hipLaunchKernelGGL(k_decproj, dim3(16), dim3(512), 0, stream,
                               hnxt, WdaT, bda, dp);
    }
    // logits for the last step (h_20 lives in hb[(NT)&1] = hb[0])
    hipLaunchKernelGGL(k_logits_fin, dim3(313), dim3(512), 0, stream,
                       NT - 1, hb + (size_t)(NT & 1) * NB * ND, WoutT, bout, out);
}